// Round 5
// baseline (349.667 us; speedup 1.0000x reference)
//
#include <hip/hip_runtime.h>
#include <hip/hip_bf16.h>

#define E_  8
#define T_  4096
#define DH_ 2048
#define DI_ 5632
#define R_  128
#define TILE_ 64
#define NT_ 72                  // T/64 + E  (worst-case padded tiles)
#define TPMAX_ (NT_*TILE_)      // 4608

typedef short bf16x8 __attribute__((ext_vector_type(8)));
typedef short bf16x4 __attribute__((ext_vector_type(4)));
typedef float f32x4 __attribute__((ext_vector_type(4)));

#define MFMA(a, b, c) __builtin_amdgcn_mfma_f32_16x16x32_bf16((a), (b), (c), 0, 0, 0)

__device__ __forceinline__ unsigned short f2bf(float f) {
  union { float f; unsigned u; } v; v.f = f;
  return (unsigned short)((v.u + 0x7fffu + ((v.u >> 16) & 1u)) >> 16);
}

__device__ __forceinline__ bf16x8 cvt8(float4 a, float4 b) {
  bf16x8 o;
  o[0] = (short)f2bf(a.x); o[1] = (short)f2bf(a.y);
  o[2] = (short)f2bf(a.z); o[3] = (short)f2bf(a.w);
  o[4] = (short)f2bf(b.x); o[5] = (short)f2bf(b.y);
  o[6] = (short)f2bf(b.z); o[7] = (short)f2bf(b.w);
  return o;
}

__device__ __forceinline__ int tile_expert(int s0, const int* off) {
  int e = 0;
#pragma unroll
  for (int q = 1; q < E_; q++) if (s0 >= off[q]) e = q;
  return e;
}

// count + offsets (pad 64) + scatter in one block
__global__ __launch_bounds__(1024) void k_route(
    const int* __restrict__ idx, int* __restrict__ off, int* __restrict__ tok)
{
  __shared__ int cnt[E_], cur[E_], offs[E_ + 1];
  const int tid = threadIdx.x;
  if (tid < E_) cnt[tid] = 0;
  __syncthreads();
  for (int t = tid; t < T_; t += 1024) atomicAdd(&cnt[idx[t]], 1);
  __syncthreads();
  if (tid == 0) {
    int a = 0;
    for (int e = 0; e < E_; e++) {
      offs[e] = a; cur[e] = a;
      a += ((cnt[e] + TILE_ - 1) / TILE_) * TILE_;
    }
    offs[E_] = a;
  }
  __syncthreads();
  if (tid <= E_) off[tid] = offs[tid];
  for (int t = tid; t < T_; t += 1024) {
    int p = atomicAdd(&cur[idx[t]], 1);
    tok[p] = t;
  }
}

// Convert all weights fp32 -> bf16 (layouts preserved)
__global__ __launch_bounds__(256) void k_cvt(
    const float* __restrict__ gA, const float* __restrict__ uA,
    const float* __restrict__ gB, const float* __restrict__ uB,
    const float* __restrict__ dA, const float* __restrict__ dB,
    const float* __restrict__ gC, const float* __restrict__ uC,
    const float* __restrict__ dC,
    short* __restrict__ gAb, short* __restrict__ uAb,
    short* __restrict__ gBb, short* __restrict__ uBb,
    short* __restrict__ dAb, short* __restrict__ dBb,
    short* __restrict__ gCb, short* __restrict__ uCb,
    short* __restrict__ dCb)
{
  long i = (long)(blockIdx.x * 256 + threadIdx.x) * 4;
  const float* s; short* d;
  if      (i <  4194304) { if (i < 2097152) { s = gA; d = gAb; } else { s = uA; d = uAb; i -= 2097152; } }
  else if (i <  9961472) { s = gB; d = gBb; i -= 4194304; }
  else if (i < 15728640) { s = uB; d = uBb; i -= 9961472; }
  else if (i < 21495808) { s = dA; d = dAb; i -= 15728640; }
  else if (i < 23592960) { s = dB; d = dBb; i -= 21495808; }
  else if (i < 23609344) { s = gC; d = gCb; i -= 23592960; }
  else if (i < 23625728) { s = uC; d = uCb; i -= 23609344; }
  else if (i < 23642112) { s = dC; d = dCb; i -= 23625728; }
  else return;
  float4 v = *(const float4*)(s + i);
  bf16x4 o;
  o[0] = (short)f2bf(v.x); o[1] = (short)f2bf(v.y);
  o[2] = (short)f2bf(v.z); o[3] = (short)f2bf(v.w);
  *(bf16x4*)(d + i) = o;
}

// Gather x rows into tile order, fp32 -> bf16 (zeros for pad rows)
__global__ __launch_bounds__(256) void k_gather(
    const float* __restrict__ x, const int* __restrict__ tok,
    short* __restrict__ Xb)
{
  const int p = blockIdx.x;
  const int t = tok[p];
  const int c = threadIdx.x * 8;
  bf16x8 o;
  if (t >= 0) {
    float4 v0 = *(const float4*)(x + (size_t)t * DH_ + c);
    float4 v1 = *(const float4*)(x + (size_t)t * DH_ + c + 4);
    o = cvt8(v0, v1);
  } else {
    o = (bf16x8){0, 0, 0, 0, 0, 0, 0, 0};
  }
  *(bf16x8*)(Xb + (size_t)p * DH_ + c) = o;
}

// Stage 1 (K-split, 64-token tiles): Hp[y][kc] partial = Xb_tile @ A[e]-chunk^T
__global__ __launch_bounds__(256) void k_stage1(
    const short* __restrict__ Xb,
    const short* __restrict__ gAb, const short* __restrict__ uAb,
    const int* __restrict__ off, float* __restrict__ Hp)
{
  const int s0 = blockIdx.x * TILE_;
  if (s0 >= off[E_]) return;
  const int e = tile_expert(s0, off);
  const int y = blockIdx.y, kc = blockIdx.z;
  const short* A = (y ? uAb : gAb) + (size_t)e * R_ * DH_ + kc * 512;

  const int tid = threadIdx.x;
  const int lane = tid & 63, wv = tid >> 6;
  const int col = lane & 15, quad = lane >> 4;

  const short* xb = Xb + (size_t)(s0 + col) * DH_ + kc * 512 + quad * 8;
  const short* ab = A + (size_t)(wv * 32 + col) * DH_ + quad * 8;

  f32x4 acc[4][2] = {};
#pragma unroll 4
  for (int k0 = 0; k0 < 512; k0 += 32) {
    bf16x8 b0 = *(const bf16x8*)(ab + k0);
    bf16x8 b1 = *(const bf16x8*)(ab + (size_t)16 * DH_ + k0);
#pragma unroll
    for (int m = 0; m < 4; m++) {
      bf16x8 a = *(const bf16x8*)(xb + (size_t)m * 16 * DH_ + k0);
      acc[m][0] = MFMA(a, b0, acc[m][0]);
      acc[m][1] = MFMA(a, b1, acc[m][1]);
    }
  }
  float* O = Hp + (size_t)(y * 4 + kc) * TPMAX_ * R_;
#pragma unroll
  for (int m = 0; m < 4; m++)
#pragma unroll
    for (int nl = 0; nl < 2; nl++)
#pragma unroll
      for (int r = 0; r < 4; r++)
        O[(size_t)(s0 + m * 16 + quad * 4 + r) * R_ + (wv * 2 + nl) * 16 + col] =
            acc[m][nl][r];
}

// Stage 1b: sum K-partials, apply C via MFMA, write Hg/Hu bf16
__global__ __launch_bounds__(256) void k_stage1b(
    const float* __restrict__ Hp,
    const short* __restrict__ gCb, const short* __restrict__ uCb,
    const int* __restrict__ off,
    short* __restrict__ Hgb, short* __restrict__ Hub)
{
  const int s0 = blockIdx.x * TILE_;
  if (s0 >= off[E_]) return;
  const int y = blockIdx.y;
  const short* C = y ? uCb : gCb;
  short* H = y ? Hub : Hgb;

  __shared__ short h1s[64][136];
  const int tid = threadIdx.x;
  {
    const int lg = tid >> 2, lq = (tid & 3) * 32;
    const float* base = Hp + ((size_t)y * 4 * TPMAX_ + s0 + lg) * R_ + lq;
    float s[32] = {};
#pragma unroll
    for (int kc = 0; kc < 4; kc++) {
      const float* p = base + (size_t)kc * TPMAX_ * R_;
#pragma unroll
      for (int q = 0; q < 8; q++) {
        float4 v = *(const float4*)(p + q * 4);
        s[q * 4 + 0] += v.x; s[q * 4 + 1] += v.y;
        s[q * 4 + 2] += v.z; s[q * 4 + 3] += v.w;
      }
    }
#pragma unroll
    for (int j = 0; j < 32; j++) h1s[lg][lq + j] = (short)f2bf(s[j]);
  }
  __syncthreads();

  const int lane = tid & 63, wv = tid >> 6;
  const int col = lane & 15, quad = lane >> 4;
  f32x4 acc2[4][2] = {};
#pragma unroll
  for (int kk = 0; kk < 4; kk++) {
    bf16x8 b[2];
#pragma unroll
    for (int nl = 0; nl < 2; nl++)
      b[nl] = *(const bf16x8*)(C + (size_t)((wv * 2 + nl) * 16 + col) * R_ +
                               kk * 32 + quad * 8);
#pragma unroll
    for (int m = 0; m < 4; m++) {
      bf16x8 a = *(const bf16x8*)&h1s[m * 16 + col][kk * 32 + quad * 8];
      acc2[m][0] = MFMA(a, b[0], acc2[m][0]);
      acc2[m][1] = MFMA(a, b[1], acc2[m][1]);
    }
  }
#pragma unroll
  for (int m = 0; m < 4; m++)
#pragma unroll
    for (int nl = 0; nl < 2; nl++)
#pragma unroll
      for (int r = 0; r < 4; r++)
        H[(size_t)(s0 + m * 16 + quad * 4 + r) * R_ + (wv * 2 + nl) * 16 + col] =
            (short)f2bf(acc2[m][nl][r]);
}

// Stage 2 (persistent per (expert, 128-col DI chunk)): weights in registers,
// loop over the expert's token tiles. Grid (E_, 44).
__global__ __launch_bounds__(256, 2) void k_stage2(
    const short* __restrict__ Hgb, const short* __restrict__ Hub,
    const short* __restrict__ gBb, const short* __restrict__ uBb,
    const short* __restrict__ dAb,
    const int* __restrict__ off, float* __restrict__ Hd1)
{
  const int e = blockIdx.x;
  const int i0 = blockIdx.y * 128;
  const int lo = off[e], hi = off[e + 1];
  if (lo >= hi) return;
  const short* Bg = gBb + (size_t)e * DI_ * R_;
  const short* Bu = uBb + (size_t)e * DI_ * R_;
  const short* Ad = dAb + (size_t)e * R_ * DI_;

  const int tid = threadIdx.x;
  const int lane = tid & 63, wv = tid >> 6;
  const int col = lane & 15, quad = lane >> 4;

  // weight slab -> registers, once per block
  bf16x8 wg[4][2], wu[4][2], wa[4][2];
#pragma unroll
  for (int kk = 0; kk < 4; kk++)
#pragma unroll
    for (int nl = 0; nl < 2; nl++) {
      size_t bo = (size_t)(i0 + (wv * 2 + nl) * 16 + col) * R_ + kk * 32 + quad * 8;
      wg[kk][nl] = *(const bf16x8*)(Bg + bo);
      wu[kk][nl] = *(const bf16x8*)(Bu + bo);
      wa[kk][nl] = *(const bf16x8*)(Ad + (size_t)((wv * 2 + nl) * 16 + col) * DI_ +
                                    i0 + kk * 32 + quad * 8);
    }

  __shared__ short hgs[64][136];
  __shared__ short hus[64][136];
  __shared__ short ZT[64][136];

  for (int s0 = lo; s0 < hi; s0 += TILE_) {
    {
      const int row = tid >> 2, seg = (tid & 3) * 32;
      const short* pg = Hgb + (size_t)(s0 + row) * R_ + seg;
      const short* pu = Hub + (size_t)(s0 + row) * R_ + seg;
#pragma unroll
      for (int q = 0; q < 4; q++) {
        *(bf16x8*)&hgs[row][seg + q * 8] = *(const bf16x8*)(pg + q * 8);
        *(bf16x8*)&hus[row][seg + q * 8] = *(const bf16x8*)(pu + q * 8);
      }
    }
    __syncthreads();   // hgs/hus ready (and prev iter fully consumed)

    f32x4 gacc[4][2] = {}, uacc[4][2] = {};
#pragma unroll
    for (int kk = 0; kk < 4; kk++)
#pragma unroll
      for (int m = 0; m < 4; m++) {
        bf16x8 ag = *(const bf16x8*)&hgs[m * 16 + col][kk * 32 + quad * 8];
        bf16x8 au = *(const bf16x8*)&hus[m * 16 + col][kk * 32 + quad * 8];
#pragma unroll
        for (int nl = 0; nl < 2; nl++) {
          gacc[m][nl] = MFMA(ag, wg[kk][nl], gacc[m][nl]);
          uacc[m][nl] = MFMA(au, wu[kk][nl], uacc[m][nl]);
        }
      }
    __syncthreads();   // all hgs/hus reads done; prev ZT reads done

#pragma unroll
    for (int m = 0; m < 4; m++)
#pragma unroll
      for (int nl = 0; nl < 2; nl++)
#pragma unroll
        for (int r = 0; r < 4; r++) {
          float g = gacc[m][nl][r];
          float z = (g / (1.0f + __expf(-g))) * uacc[m][nl][r];
          ZT[m * 16 + quad * 4 + r][(wv * 2 + nl) * 16 + col] = (short)f2bf(z);
        }
    __syncthreads();   // ZT ready

    f32x4 dacc[4][2] = {};
#pragma unroll
    for (int kk2 = 0; kk2 < 4; kk2++)
#pragma unroll
      for (int m = 0; m < 4; m++) {
        bf16x8 za = *(const bf16x8*)&ZT[m * 16 + col][kk2 * 32 + quad * 8];
        dacc[m][0] = MFMA(za, wa[kk2][0], dacc[m][0]);
        dacc[m][1] = MFMA(za, wa[kk2][1], dacc[m][1]);
      }
#pragma unroll
    for (int m = 0; m < 4; m++)
#pragma unroll
      for (int nl = 0; nl < 2; nl++)
#pragma unroll
        for (int r = 0; r < 4; r++)
          atomicAdd(&Hd1[(size_t)(s0 + m * 16 + quad * 4 + r) * R_ +
                         (wv * 2 + nl) * 16 + col],
                    dacc[m][nl][r]);
  }
}

// Apply dC once: Hd2 = (Hd1 @ dC^T) in bf16  (grid NT_)
__global__ __launch_bounds__(256) void k_applyCd(
    const float* __restrict__ Hd1, const short* __restrict__ dCb,
    const int* __restrict__ off, short* __restrict__ Hd2b)
{
  const int s0 = blockIdx.x * TILE_;
  if (s0 >= off[E_]) return;
  const int tid = threadIdx.x;
  const int lane = tid & 63, wv = tid >> 6;
  const int col = lane & 15, quad = lane >> 4;

  bf16x8 wc[4][2];
#pragma unroll
  for (int kk = 0; kk < 4; kk++)
#pragma unroll
    for (int nl = 0; nl < 2; nl++)
      wc[kk][nl] = *(const bf16x8*)(dCb + (size_t)((wv * 2 + nl) * 16 + col) * R_ +
                                    kk * 32 + quad * 8);

  f32x4 acc[4][2] = {};
#pragma unroll
  for (int kk = 0; kk < 4; kk++)
#pragma unroll
    for (int m = 0; m < 4; m++) {
      const float* hp = Hd1 + (size_t)(s0 + m * 16 + col) * R_ + kk * 32 + quad * 8;
      float4 v0 = *(const float4*)hp;
      float4 v1 = *(const float4*)(hp + 4);
      bf16x8 a = cvt8(v0, v1);
      acc[m][0] = MFMA(a, wc[kk][0], acc[m][0]);
      acc[m][1] = MFMA(a, wc[kk][1], acc[m][1]);
    }
#pragma unroll
  for (int m = 0; m < 4; m++)
#pragma unroll
    for (int nl = 0; nl < 2; nl++)
#pragma unroll
      for (int r = 0; r < 4; r++)
        Hd2b[(size_t)(s0 + m * 16 + quad * 4 + r) * R_ + (wv * 2 + nl) * 16 + col] =
            (short)f2bf(acc[m][nl][r]);
}

// Stage 3 (persistent streaming GEMM, no LDS/barriers): out = Hd2 @ dB^T + bias
// Grid (E_, 16 d-chunks, 4 tile-splits)
__global__ __launch_bounds__(256, 2) void k_stage3(
    const short* __restrict__ Hd2b, const short* __restrict__ dBb,
    const float* __restrict__ dbias,
    const int* __restrict__ off, const int* __restrict__ tok,
    float* __restrict__ out)
{
  const int e = blockIdx.x;
  const int d0 = blockIdx.y * 128;
  const int lo = off[e], hi = off[e + 1];
  const int tid = threadIdx.x;
  const int lane = tid & 63, wv = tid >> 6;
  const int col = lane & 15, quad = lane >> 4;

  bf16x8 wb[4][2];
#pragma unroll
  for (int kk = 0; kk < 4; kk++)
#pragma unroll
    for (int nl = 0; nl < 2; nl++)
      wb[kk][nl] = *(const bf16x8*)(dBb + (size_t)e * DH_ * R_ +
                                    (size_t)(d0 + (wv * 2 + nl) * 16 + col) * R_ +
                                    kk * 32 + quad * 8);
  float bias[2];
#pragma unroll
  for (int nl = 0; nl < 2; nl++)
    bias[nl] = dbias[(size_t)e * DH_ + d0 + (wv * 2 + nl) * 16 + col];

  for (int s0 = lo + (int)blockIdx.z * TILE_; s0 < hi; s0 += 4 * TILE_) {
    f32x4 acc[4][2] = {};
#pragma unroll
    for (int kk = 0; kk < 4; kk++)
#pragma unroll
      for (int m = 0; m < 4; m++) {
        bf16x8 a = *(const bf16x8*)(Hd2b + (size_t)(s0 + m * 16 + col) * R_ +
                                    kk * 32 + quad * 8);
        acc[m][0] = MFMA(a, wb[kk][0], acc[m][0]);
        acc[m][1] = MFMA(a, wb[kk][1], acc[m][1]);
      }
#pragma unroll
    for (int m = 0; m < 4; m++)
#pragma unroll
      for (int r = 0; r < 4; r++) {
        int t = tok[s0 + m * 16 + quad * 4 + r];
        if (t < 0) continue;
#pragma unroll
        for (int nl = 0; nl < 2; nl++) {
          int d = d0 + (wv * 2 + nl) * 16 + col;
          out[(size_t)t * DH_ + d] = acc[m][nl][r] + bias[nl];
        }
      }
  }
}

extern "C" void kernel_launch(void* const* d_in, const int* in_sizes, int n_in,
                              void* d_out, int out_size, void* d_ws, size_t ws_size,
                              hipStream_t stream)
{
  (void)in_sizes; (void)n_in; (void)out_size; (void)ws_size;
  const float* x     = (const float*)d_in[0];
  const int*   idx   = (const int*)d_in[1];
  const float* gA    = (const float*)d_in[2];
  const float* gC    = (const float*)d_in[3];
  const float* gBw   = (const float*)d_in[4];
  const float* uA    = (const float*)d_in[5];
  const float* uC    = (const float*)d_in[6];
  const float* uBw   = (const float*)d_in[7];
  const float* dA    = (const float*)d_in[8];
  const float* dC    = (const float*)d_in[9];
  const float* dBw   = (const float*)d_in[10];
  const float* dbias = (const float*)d_in[11];
  float* out = (float*)d_out;

  char* ws = (char*)d_ws;
  int* off = (int*)ws;                          // 9 ints
  int* tok = (int*)(ws + 512);                  // 4608 ints       -> 18944
  float* Hd1 = (float*)(ws + 32768);            // 4608*128 f32    -> 2392064
  float* Hp  = (float*)(ws + 2392064);          // 8*4608*128 f32  -> 21266432
  short* Xb  = (short*)(ws + 21266432);         // 4608*2048 bf16  -> 40140800
  short* Hgb = (short*)(ws + 40140800);         // 4608*128 bf16   -> 41320448
  short* Hub = (short*)(ws + 41320448);         //                 -> 42500096
  short* Hd2b= (short*)(ws + 42500096);         // 4608*128 bf16   -> 43679744
  short* gAb = (short*)(ws + 43679744);         // 8*128*2048      -> 47874048
  short* uAb = (short*)(ws + 47874048);         //                 -> 52068352
  short* gBb = (short*)(ws + 52068352);         // 8*5632*128      -> 63602688
  short* uBb = (short*)(ws + 63602688);         //                 -> 75137024
  short* dAb = (short*)(ws + 75137024);         // 8*128*5632      -> 86671360
  short* dBb = (short*)(ws + 86671360);         // 8*2048*128      -> 90865664
  short* gCb = (short*)(ws + 90865664);         // 128*128         -> 90898432
  short* uCb = (short*)(ws + 90898432);         //                 -> 90931200
  short* dCb = (short*)(ws + 90931200);         //                 -> 90963968

  hipMemsetAsync(tok, 0xFF, TPMAX_ * sizeof(int), stream);
  hipMemsetAsync(Hd1, 0, (size_t)TPMAX_ * R_ * sizeof(float), stream);

  k_cvt    <<<dim3(23088), 256, 0, stream>>>(gA, uA, gBw, uBw, dA, dBw, gC, uC, dC,
                                             gAb, uAb, gBb, uBb, dAb, dBb, gCb, uCb, dCb);
  k_route  <<<1, 1024, 0, stream>>>(idx, off, tok);
  k_gather <<<dim3(TPMAX_), 256, 0, stream>>>(x, tok, Xb);
  k_stage1 <<<dim3(NT_, 2, 4), 256, 0, stream>>>(Xb, gAb, uAb, off, Hp);
  k_stage1b<<<dim3(NT_, 2), 256, 0, stream>>>(Hp, gCb, uCb, off, Hgb, Hub);
  k_stage2 <<<dim3(E_, 44), 256, 0, stream>>>(Hgb, Hub, gBb, uBb, dAb, off, Hd1);
  k_applyCd<<<dim3(NT_), 256, 0, stream>>>(Hd1, dCb, off, Hd2b);
  k_stage3 <<<dim3(E_, 16, 4), 256, 0, stream>>>(Hd2b, dBb, dbias, off, tok, out);
}